// Round 5
// baseline (520.228 us; speedup 1.0000x reference)
//
#include <hip/hip_runtime.h>
#include <hip/hip_bf16.h>

typedef __attribute__((ext_vector_type(8))) short bf16x8;
typedef __attribute__((ext_vector_type(4))) float f32x4;

#define NB 8
#define NC 256
#define ND 32
#define NN 16384
#define TILE_P 32

#define MFMA16(a, b, c) __builtin_amdgcn_mfma_f32_16x16x32_bf16((a), (b), (c), 0, 0, 0)

__device__ __forceinline__ float u2f(unsigned short u) {
  union { unsigned int i; float f; } v; v.i = ((unsigned int)u) << 16; return v.f;
}
__device__ __forceinline__ unsigned short f2u(float f) {
  union { float f; unsigned int i; } v; v.f = f;
  unsigned int x = v.i;
  return (unsigned short)((x + 0x7fffu + ((x >> 16) & 1u)) >> 16);  // RNE
}
__device__ __forceinline__ float ldg(const void* p, size_t i, int isbf) {
  return isbf ? u2f(((const unsigned short*)p)[i]) : ((const float*)p)[i];
}
// swizzled LDS addressing: row p (512B rows), byte col colb, 16B-block XOR swizzle.
__device__ __forceinline__ char* lds_at(char* base, int p, int colb) {
  return base + (p << 9) + (colb ^ ((p & 7) << 4));
}

// ---------------- dtype detect ----------------
__global__ __launch_bounds__(256) void detect_kernel(const void* __restrict__ x,
                                                     int* __restrict__ flag) {
  __shared__ int red[4];
  const unsigned int* w = (const unsigned int*)x;
  int cnt = 0;
  for (int i = threadIdx.x; i < 4096; i += 256) {
    unsigned int e = (w[i] >> 7) & 0xFFu;
    cnt += (e >= 100u && e <= 135u) ? 1 : 0;
  }
  for (int off = 32; off; off >>= 1) cnt += __shfl_xor(cnt, off, 64);
  if ((threadIdx.x & 63) == 0) red[threadIdx.x >> 6] = cnt;
  __syncthreads();
  if (threadIdx.x == 0)
    flag[0] = (red[0] + red[1] + red[2] + red[3] > 2048) ? 1 : 0;
}

// ---------------- prep: pack Wq/Wp/Wkv into per-lane MFMA A-fragment layout ----------------
// slot = (kt*NMB + mb)*64 + lane ; lane holds W[o = mb*16+(lane&15)][k = kt*32+8*(lane>>4)+e]
__global__ __launch_bounds__(256) void prep_weights(
    const void* __restrict__ wq, const void* __restrict__ wp,
    const void* __restrict__ wkv, const int* __restrict__ flag,
    unsigned short* __restrict__ WqPh, unsigned short* __restrict__ WqPl,
    unsigned short* __restrict__ WpPh, unsigned short* __restrict__ WpPl,
    unsigned short* __restrict__ WkPh, unsigned short* __restrict__ WkPl) {
  int isbf = flag[0];
  int idx = blockIdx.x * 256 + threadIdx.x;  // 17408 total
  const void* w;
  unsigned short *Ph, *Pl;
  int slot, o, k0;
  if (idx < 16384) {
    int mat = idx >> 13;
    slot = idx & 8191;
    int lane = slot & 63;
    int mbkt = slot >> 6;
    int mb = mbkt & 15, kt = mbkt >> 4;
    o = mb * 16 + (lane & 15);
    k0 = kt * 32 + (lane >> 4) * 8;
    w = mat ? wp : wq;
    Ph = mat ? WpPh : WqPh;
    Pl = mat ? WpPl : WqPl;
  } else {
    slot = idx - 16384;  // [0, 1024)
    int lane = slot & 63;
    int grp = slot >> 6;
    int mb = grp & 1, kt = grp >> 1;
    o = mb * 16 + (lane & 15);
    k0 = kt * 32 + (lane >> 4) * 8;
    w = wkv;
    Ph = WkPh;
    Pl = WkPl;
  }
  unsigned short h[8], lo[8];
#pragma unroll
  for (int e = 0; e < 8; e++) {
    float v = ldg(w, (size_t)o * NC + k0 + e, isbf);
    unsigned short hh = f2u(v);
    h[e] = hh;
    lo[e] = isbf ? (unsigned short)0 : f2u(v - u2f(hh));
  }
  uint4 ph, pl;
  ph.x = h[0] | ((unsigned)h[1] << 16);
  ph.y = h[2] | ((unsigned)h[3] << 16);
  ph.z = h[4] | ((unsigned)h[5] << 16);
  ph.w = h[6] | ((unsigned)h[7] << 16);
  pl.x = lo[0] | ((unsigned)lo[1] << 16);
  pl.y = lo[2] | ((unsigned)lo[3] << 16);
  pl.z = lo[4] | ((unsigned)lo[5] << 16);
  pl.w = lo[6] | ((unsigned)lo[7] << 16);
  *(uint4*)(Ph + (size_t)slot * 8) = ph;
  *(uint4*)(Pl + (size_t)slot * 8) = pl;
}

// ---------------- fused kv + ctx partials ----------------
// Block = (b, 32-px chunk). Computes kv = affine(Wkv@X) for its 32 px via MFMA,
// then E = exp(kv) (m==0, validated R4), transposes E/K hi/lo through an 8KB LDS
// tile, and emits the 32x32 S-partial (3 MFMA) + Z-partial. No Kh/Kl round-trip.
__global__ __launch_bounds__(256, 4) void kv_ctx(
    const void* __restrict__ x, const unsigned short* __restrict__ WkPh,
    const unsigned short* __restrict__ WkPl, const void* __restrict__ kv_scale,
    const void* __restrict__ kv_bias, const int* __restrict__ flag,
    float* __restrict__ Spart, float* __restrict__ Zpart) {
  __shared__ __align__(16) char pool[32768];
  const int isbf = flag[0];
  const int tid = threadIdx.x;
  const int bid = blockIdx.x;          // 4096 = 8 b x 512 chunks
  const int b = bid >> 9;
  const int n0 = (bid & 511) * 32;
  const int w = tid >> 6, l = tid & 63, g = l >> 4, cc = l & 15;
  const int mi = w >> 1, ni = w & 1;
  const f32x4 zero4 = {0.f, 0.f, 0.f, 0.f};

  // ---- stage X tile 32px x 256ch: hi at pool[0,16K), lo at pool[16K,32K) ----
  {
    const int c0 = (tid >> 3) * 8;
    const int pq = (tid & 7) * 4;
    unsigned short hi[8][4], lo[8][4];
    if (isbf) {
      const unsigned short* xp =
          (const unsigned short*)x + ((size_t)(b * NC + c0)) * NN + n0 + pq;
#pragma unroll
      for (int i = 0; i < 8; i++) {
        ushort4 r = *(const ushort4*)(xp + (size_t)i * NN);
        hi[i][0] = r.x; hi[i][1] = r.y; hi[i][2] = r.z; hi[i][3] = r.w;
      }
    } else {
      const float* xp = (const float*)x + ((size_t)(b * NC + c0)) * NN + n0 + pq;
#pragma unroll
      for (int i = 0; i < 8; i++) {
        float4 v = *(const float4*)(xp + (size_t)i * NN);
        float vv[4] = {v.x, v.y, v.z, v.w};
#pragma unroll
        for (int j = 0; j < 4; j++) {
          unsigned short hh = f2u(vv[j]);
          hi[i][j] = hh;
          lo[i][j] = f2u(vv[j] - u2f(hh));
        }
      }
    }
#pragma unroll
    for (int j = 0; j < 4; j++) {
      int p = pq + j;
      uint4 wv;
      wv.x = hi[0][j] | ((unsigned)hi[1][j] << 16);
      wv.y = hi[2][j] | ((unsigned)hi[3][j] << 16);
      wv.z = hi[4][j] | ((unsigned)hi[5][j] << 16);
      wv.w = hi[6][j] | ((unsigned)hi[7][j] << 16);
      *(uint4*)lds_at(pool, p, c0 * 2) = wv;
      if (!isbf) {
        uint4 wl2;
        wl2.x = lo[0][j] | ((unsigned)lo[1][j] << 16);
        wl2.y = lo[2][j] | ((unsigned)lo[3][j] << 16);
        wl2.z = lo[4][j] | ((unsigned)lo[5][j] << 16);
        wl2.w = lo[6][j] | ((unsigned)lo[7][j] << 16);
        *(uint4*)lds_at(pool + 16384, p, c0 * 2) = wl2;
      }
    }
  }
  __syncthreads();

  // ---- kv GEMM quarter: wave (mi = d-half, ni = px-half) ----
  f32x4 acc = zero4;
  {
    const bf16x8* Ah = (const bf16x8*)WkPh;
    const bf16x8* Al = (const bf16x8*)WkPl;
#pragma unroll
    for (int kt = 0; kt < 8; kt++) {
      bf16x8 xb = *(const bf16x8*)lds_at(pool, ni * 16 + cc, kt * 64 + 16 * g);
      bf16x8 a = Ah[(kt * 2 + mi) * 64 + l];
      acc = MFMA16(a, xb, acc);
      if (!isbf) {
        bf16x8 xl = *(const bf16x8*)lds_at(pool + 16384, ni * 16 + cc, kt * 64 + 16 * g);
        bf16x8 al = Al[(kt * 2 + mi) * 64 + l];
        acc = MFMA16(a, xl, acc);
        acc = MFMA16(al, xb, acc);
      }
    }
  }

  // ---- affine + exp (m == 0) + hi/lo splits; Z partial via px shuffles ----
  unsigned short khv[4], klv[4], ehv[4], elv[4];
  float zv[4];
#pragma unroll
  for (int rr = 0; rr < 4; rr++) {
    int d = mi * 16 + 4 * g + rr;
    float v = acc[rr] * ldg(kv_scale, d, isbf) + ldg(kv_bias, d, isbf);
    unsigned short kh = f2u(v);
    khv[rr] = kh;
    klv[rr] = f2u(v - u2f(kh));
    float e = __expf(v);
    zv[rr] = e;
    unsigned short eh = f2u(e);
    ehv[rr] = eh;
    elv[rr] = f2u(e - u2f(eh));
  }
#pragma unroll
  for (int rr = 0; rr < 4; rr++) {
    zv[rr] += __shfl_xor(zv[rr], 1, 64);
    zv[rr] += __shfl_xor(zv[rr], 2, 64);
    zv[rr] += __shfl_xor(zv[rr], 4, 64);
    zv[rr] += __shfl_xor(zv[rr], 8, 64);
  }
  if (cc == 0) {
#pragma unroll
    for (int rr = 0; rr < 4; rr++)
      Zpart[((size_t)bid * 2 + ni) * ND + mi * 16 + 4 * g + rr] = zv[rr];
  }
  __syncthreads();  // staging reads done -> overlay tiles

  // ---- write E/K tiles [32 rows][32 px] bf16, 64B rows, per-row XOR swizzle ----
  {
    char* Eh = pool;
    char* El = pool + 2048;
    char* Kh = pool + 4096;
    char* Kl = pool + 6144;
    int px = ni * 16 + cc;
#pragma unroll
    for (int rr = 0; rr < 4; rr++) {
      int d = mi * 16 + 4 * g + rr;
      int off = d * 64 + ((px * 2) ^ ((d & 3) << 4));
      *(unsigned short*)(Eh + off) = ehv[rr];
      *(unsigned short*)(El + off) = elv[rr];
      *(unsigned short*)(Kh + off) = khv[rr];
      *(unsigned short*)(Kl + off) = klv[rr];
    }
  }
  __syncthreads();

  // ---- S quarter: wave (mq = d-half, eq = e-half); K dim = 32 px (one step) ----
  {
    char* Eh = pool;
    char* El = pool + 2048;
    char* Kh = pool + 4096;
    char* Kl = pool + 6144;
    int ra = mi * 16 + cc;  // A rows: d
    int rb = ni * 16 + cc;  // B rows: e
    int ca = (16 * g) ^ ((ra & 3) << 4);
    int cb = (16 * g) ^ ((rb & 3) << 4);
    bf16x8 aEh = *(const bf16x8*)(Eh + ra * 64 + ca);
    bf16x8 aEl = *(const bf16x8*)(El + ra * 64 + ca);
    bf16x8 bKh = *(const bf16x8*)(Kh + rb * 64 + cb);
    bf16x8 bKl = *(const bf16x8*)(Kl + rb * 64 + cb);
    f32x4 s = zero4;
    s = MFMA16(aEh, bKh, s);
    s = MFMA16(aEh, bKl, s);
    s = MFMA16(aEl, bKh, s);
    float* sp = Spart + (size_t)bid * 1024;
#pragma unroll
    for (int rr = 0; rr < 4; rr++)
      sp[(mi * 16 + 4 * g + rr) * 32 + ni * 16 + cc] = s[rr];
  }
}

// ---------------- reduce partials + divide -> ctx[b][d][e] ----------------
// block = (b, d): sums 512 S chunks (coalesced 128B rows) and 1024 Z slots.
__global__ __launch_bounds__(256) void ctx_redfin(const float* __restrict__ Spart,
                                                  const float* __restrict__ Zpart,
                                                  float* __restrict__ ctx) {
  __shared__ float rs[256], rz[256];
  const int bid = blockIdx.x;  // 256 = 8 b x 32 d
  const int b = bid >> 5, d = bid & 31;
  const int t = threadIdx.x, e = t & 31, j = t >> 5;
  float s = 0.f;
  for (int c = j; c < 512; c += 8)
    s += Spart[((size_t)(b * 512 + c)) * 1024 + d * 32 + e];
  float z = 0.f;
  for (int k = t; k < 1024; k += 256)
    z += Zpart[((size_t)(b * 1024 + k)) * ND + d];
  rs[t] = s; rz[t] = z;
  __syncthreads();
  if (t < 128) { rs[t] += rs[t + 128]; rz[t] += rz[t + 128]; }
  __syncthreads();
  if (t < 64) { rs[t] += rs[t + 64]; rz[t] += rz[t + 64]; }
  __syncthreads();
  if (t < 32) {
    float ss = rs[t] + rs[t + 32];
    float zz = rz[t] + rz[t + 32];
    zz += __shfl_xor(zz, 1, 64);
    zz += __shfl_xor(zz, 2, 64);
    zz += __shfl_xor(zz, 4, 64);
    zz += __shfl_xor(zz, 8, 64);
    zz += __shfl_xor(zz, 16, 64);
    ctx[((size_t)b * ND + d) * ND + t] = ss / zz;
  }
}

// ---------------- fused: q GEMM -> softmax(D) -> ctx matvec -> relu -> out GEMM ----------------
// R3-proven structure (169us): single-shot full-tile staging, pool 69632, 2 blocks/CU.
// Only change vs R3: dropped the two 2^-18 cross terms (al*xl in GEMM1, cAl*bl in ctx).
#define XT_OFF 0
#define XTL_OFF 16384
#define SMH_OFF 32768
#define SML_OFF 49152
#define YTH_OFF 0
#define YTL_OFF 16384
#define OT_OFF 32768

__global__ __launch_bounds__(256, 2) void fused_main(
    const void* __restrict__ x,
    const unsigned short* __restrict__ WqPh, const unsigned short* __restrict__ WqPl,
    const unsigned short* __restrict__ WpPh, const unsigned short* __restrict__ WpPl,
    const void* __restrict__ q_scale, const void* __restrict__ q_bias,
    const void* __restrict__ p_scale, const void* __restrict__ p_bias,
    const float* __restrict__ ctx, const int* __restrict__ flag,
    void* __restrict__ out) {
  __shared__ __align__(16) char pool[69632];
  __shared__ float qs_l[NC], qb_l[NC], ps_l[NC], pb_l[NC];
  const int isbf = flag[0];
  const int tid = threadIdx.x;
  const int b = blockIdx.x >> 9;
  const int n0 = (blockIdx.x & 511) * TILE_P;
  const int w = tid >> 6;
  const int l = tid & 63;
  const int g = l >> 4;
  const int cc = l & 15;
  const f32x4 zero4 = {0.f, 0.f, 0.f, 0.f};

  qs_l[tid] = ldg(q_scale, tid, isbf);
  qb_l[tid] = ldg(q_bias, tid, isbf);
  ps_l[tid] = ldg(p_scale, tid, isbf);
  pb_l[tid] = ldg(p_bias, tid, isbf);

  // ctx A-fragments: A[m=e][k=d] = ctx[d][e], hi/lo
  bf16x8 cAh[2], cAl[2];
  {
    const float* cb = ctx + (size_t)b * ND * ND;
#pragma unroll
    for (int mp = 0; mp < 2; mp++) {
      bf16x8 ah, al;
#pragma unroll
      for (int el = 0; el < 8; el++) {
        float v = cb[(8 * g + el) * ND + 16 * mp + cc];
        unsigned short hh = f2u(v);
        ah[el] = (short)hh;
        al[el] = (short)f2u(v - u2f(hh));
      }
      cAh[mp] = ah; cAl[mp] = al;
    }
  }

  // ---- stage X tile: XT[p(32)][c(256)] bf16 hi (+lo fp32 mode) ----
  {
    const int c0 = (tid >> 3) * 8;
    const int pq = (tid & 7) * 4;
    unsigned short hi[8][4], lo[8][4];
    if (isbf) {
      const unsigned short* xp =
          (const unsigned short*)x + ((size_t)(b * NC + c0)) * NN + n0 + pq;
#pragma unroll
      for (int i = 0; i < 8; i++) {
        ushort4 r = *(const ushort4*)(xp + (size_t)i * NN);
        hi[i][0] = r.x; hi[i][1] = r.y; hi[i][2] = r.z; hi[i][3] = r.w;
      }
    } else {
      const float* xp = (const float*)x + ((size_t)(b * NC + c0)) * NN + n0 + pq;
#pragma unroll
      for (int i = 0; i < 8; i++) {
        float4 v = *(const float4*)(xp + (size_t)i * NN);
        float vv[4] = {v.x, v.y, v.z, v.w};
#pragma unroll
        for (int j = 0; j < 4; j++) {
          unsigned short hh = f2u(vv[j]);
          hi[i][j] = hh;
          lo[i][j] = f2u(vv[j] - u2f(hh));
        }
      }
    }
#pragma unroll
    for (int j = 0; j < 4; j++) {
      int p = pq + j;
      uint4 wv;
      wv.x = hi[0][j] | ((unsigned)hi[1][j] << 16);
      wv.y = hi[2][j] | ((unsigned)hi[3][j] << 16);
      wv.z = hi[4][j] | ((unsigned)hi[5][j] << 16);
      wv.w = hi[6][j] | ((unsigned)hi[7][j] << 16);
      *(uint4*)lds_at(pool + XT_OFF, p, c0 * 2) = wv;
      if (!isbf) {
        uint4 wl2;
        wl2.x = lo[0][j] | ((unsigned)lo[1][j] << 16);
        wl2.y = lo[2][j] | ((unsigned)lo[3][j] << 16);
        wl2.z = lo[4][j] | ((unsigned)lo[5][j] << 16);
        wl2.w = lo[6][j] | ((unsigned)lo[7][j] << 16);
        *(uint4*)lds_at(pool + XTL_OFF, p, c0 * 2) = wl2;
      }
    }
  }
  __syncthreads();

  // ---- GEMM1: q = Wq @ x (fp32: 3-term) ----
  f32x4 acc[4][2];
#pragma unroll
  for (int mi = 0; mi < 4; mi++) { acc[mi][0] = zero4; acc[mi][1] = zero4; }
  {
    const bf16x8* Aq = (const bf16x8*)WqPh;
    const bf16x8* Aql = (const bf16x8*)WqPl;
#pragma unroll
    for (int kt = 0; kt < 8; kt++) {
      bf16x8 xb0 = *(const bf16x8*)lds_at(pool + XT_OFF, cc, kt * 64 + 16 * g);
      bf16x8 xb1 = *(const bf16x8*)lds_at(pool + XT_OFF, 16 + cc, kt * 64 + 16 * g);
      bf16x8 av[4];
#pragma unroll
      for (int mi = 0; mi < 4; mi++) av[mi] = Aq[(kt * 16 + w * 4 + mi) * 64 + l];
#pragma unroll
      for (int mi = 0; mi < 4; mi++) {
        acc[mi][0] = MFMA16(av[mi], xb0, acc[mi][0]);
        acc[mi][1] = MFMA16(av[mi], xb1, acc[mi][1]);
      }
      if (!isbf) {
        bf16x8 xl0 = *(const bf16x8*)lds_at(pool + XTL_OFF, cc, kt * 64 + 16 * g);
        bf16x8 xl1 = *(const bf16x8*)lds_at(pool + XTL_OFF, 16 + cc, kt * 64 + 16 * g);
#pragma unroll
        for (int mi = 0; mi < 4; mi++) {
          bf16x8 al2 = Aql[(kt * 16 + w * 4 + mi) * 64 + l];
          acc[mi][0] = MFMA16(av[mi], xl0, acc[mi][0]);
          acc[mi][1] = MFMA16(av[mi], xl1, acc[mi][1]);
          acc[mi][0] = MFMA16(al2, xb0, acc[mi][0]);
          acc[mi][1] = MFMA16(al2, xb1, acc[mi][1]);
        }
      }
    }
  }

  // ---- softmax over D per (head,pixel); E hi/lo -> SM tiles ----
  float inv_s[2][2];
#pragma unroll
  for (int hp = 0; hp < 2; hp++) {
#pragma unroll
    for (int ni = 0; ni < 2; ni++) {
      float e8[8];
      float mx = -3.0e38f;
#pragma unroll
      for (int mi2 = 0; mi2 < 2; mi2++) {
#pragma unroll
        for (int r = 0; r < 4; r++) {
          int o = w * 64 + (2 * hp + mi2) * 16 + 4 * g + r;
          float v = acc[2 * hp + mi2][ni][r] * qs_l[o] + qb_l[o];
          e8[mi2 * 4 + r] = v;
          mx = fmaxf(mx, v);
        }
      }
      mx = fmaxf(mx, __shfl_xor(mx, 16, 64));
      mx = fmaxf(mx, __shfl_xor(mx, 32, 64));
      float s = 0.f;
#pragma unroll
      for (int i2 = 0; i2 < 8; i2++) { e8[i2] = __expf(e8[i2] - mx); s += e8[i2]; }
      s += __shfl_xor(s, 16, 64);
      s += __shfl_xor(s, 32, 64);
      inv_s[hp][ni] = 1.f / s;
      int p = ni * 16 + cc;
#pragma unroll
      for (int mi2 = 0; mi2 < 2; mi2++) {
        int colb = (w * 64 + (2 * hp + mi2) * 16 + 4 * g) * 2;
        unsigned short h[4], lo2[4];
#pragma unroll
        for (int r = 0; r < 4; r++) {
          float ev = e8[mi2 * 4 + r];
          unsigned short hh = f2u(ev);
          h[r] = hh;
          lo2[r] = f2u(ev - u2f(hh));
        }
        uint2 wh, wl2;
        wh.x = h[0] | ((unsigned)h[1] << 16);
        wh.y = h[2] | ((unsigned)h[3] << 16);
        wl2.x = lo2[0] | ((unsigned)lo2[1] << 16);
        wl2.y = lo2[2] | ((unsigned)lo2[3] << 16);
        *(uint2*)lds_at(pool + SMH_OFF, p, colb) = wh;
        *(uint2*)lds_at(pool + SML_OFF, p, colb) = wl2;
      }
    }
  }
  __syncthreads();  // (1) all XT reads done; SM tiles complete

  // ---- ctx GEMM: att = ctx^T @ E (3-term), /s, relu, hi/lo -> YT tiles ----
#pragma unroll
  for (int hp = 0; hp < 2; hp++) {
    f32x4 cacc[2][2];
#pragma unroll
    for (int mp = 0; mp < 2; mp++) { cacc[mp][0] = zero4; cacc[mp][1] = zero4; }
#pragma unroll
    for (int ni = 0; ni < 2; ni++) {
      int p = ni * 16 + cc;
      int colb = ((2 * w + hp) * 32 + 8 * g) * 2;
      bf16x8 bh = *(const bf16x8*)lds_at(pool + SMH_OFF, p, colb);
      bf16x8 bl = *(const bf16x8*)lds_at(pool + SML_OFF, p, colb);
#pragma unroll
      for (int mp = 0; mp < 2; mp++) {
        cacc[mp][ni] = MFMA16(cAh[mp], bh, cacc[mp][ni]);
        cacc[mp][ni] = MFMA16(cAh[mp], bl, cacc[mp][ni]);
        cacc[mp][ni] = MFMA16(cAl[mp], bh, cacc[mp][ni]);
      }
    }
#pragma unroll
    for (int mp = 0; mp < 2; mp++) {
#pragma unroll
      for (int ni = 0; ni < 2; ni++) {
        int p = ni * 16 + cc;
        float iv = inv_s[hp][ni];
        unsigned short h[4], lo2[4];
#pragma unroll
        for (int r = 0; r < 4; r++) {
          float y = fmaxf(cacc[mp][ni][r] * iv, 0.f);
          unsigned short hh = f2u(y);
          h[r] = hh;
          lo2[r] = f2u(y - u2f(hh));
        }
        int colb = ((2 * w + hp) * 32 + mp * 16 + 4 * g) * 2;
        uint2 wh, wl2;
        wh.x = h[0] | ((unsigned)h[1] << 16);
        wh.y = h[2] | ((unsigned)h[3] << 16);
        wl2.x = lo2[0] | ((unsigned)lo2[1] << 16);
        wl2.y = lo2[2] | ((unsigned)lo2[3] << 16);
        *(uint2*)lds_at(pool + YTH_OFF, p, colb) = wh;
        *(uint2*)lds_at(pool + YTL_OFF, p, colb) = wl2;
      }
    }
  }
  __syncthreads();  // (2) YT tiles complete

  // ---- GEMM2: out = Wp @ relu(att) ----
  f32x4 oacc[4][2];
#pragma unroll
  for (int mi = 0; mi < 4; mi++) { oacc[mi][0] = zero4; oacc[mi][1] = zero4; }
  {
    const bf16x8* Ap = (const bf16x8*)WpPh;
    const bf16x8* Apl = (const bf16x8*)WpPl;
#pragma unroll
    for (int kt = 0; kt < 8; kt++) {
      bf16x8 yh0 = *(const bf16x8*)lds_at(pool + YTH_OFF, cc, kt * 64 + 16 * g);
      bf16x8 yh1 = *(const bf16x8*)lds_at(pool + YTH_OFF, 16 + cc, kt * 64 + 16 * g);
      bf16x8 yl0 = *(const bf16x8*)lds_at(pool + YTL_OFF, cc, kt * 64 + 16 * g);
      bf16x8 yl1 = *(const bf16x8*)lds_at(pool + YTL_OFF, 16 + cc, kt * 64 + 16 * g);
      bf16x8 av[4];
#pragma unroll
      for (int mi = 0; mi < 4; mi++) av[mi] = Ap[(kt * 16 + w * 4 + mi) * 64 + l];
#pragma unroll
      for (int mi = 0; mi < 4; mi++) {
        oacc[mi][0] = MFMA16(av[mi], yh0, oacc[mi][0]);
        oacc[mi][1] = MFMA16(av[mi], yh1, oacc[mi][1]);
        oacc[mi][0] = MFMA16(av[mi], yl0, oacc[mi][0]);
        oacc[mi][1] = MFMA16(av[mi], yl1, oacc[mi][1]);
      }
      if (!isbf) {
#pragma unroll
        for (int mi = 0; mi < 4; mi++) {
          bf16x8 al2 = Apl[(kt * 16 + w * 4 + mi) * 64 + l];
          oacc[mi][0] = MFMA16(al2, yh0, oacc[mi][0]);
          oacc[mi][1] = MFMA16(al2, yh1, oacc[mi][1]);
        }
      }
    }
  }

  // ---- epilogue: affine -> OT (channel-major) -> coalesced global store ----
  {
    char* OT = pool + OT_OFF;
#pragma unroll
    for (int mi = 0; mi < 4; mi++) {
#pragma unroll
      for (int ni = 0; ni < 2; ni++) {
#pragma unroll
        for (int r = 0; r < 4; r++) {
          int o = w * 64 + mi * 16 + 4 * g + r;
          float v = oacc[mi][ni][r] * ps_l[o] + pb_l[o];
          int p = ni * 16 + cc;
          if (isbf)
            *(unsigned short*)(OT + o * 80 + p * 2) = f2u(v);
          else
            *(float*)(OT + o * 144 + p * 4) = v;
        }
      }
    }
  }
  __syncthreads();  // (3) OT complete
  {
    char* OT = pool + OT_OFF;
    int o = tid;
    size_t gbase = ((size_t)(b * NC + o)) * NN + n0;
    if (isbf) {
      unsigned short* po = (unsigned short*)out + gbase;
#pragma unroll
      for (int k = 0; k < 4; k++)
        *(uint4*)(po + k * 8) = *(const uint4*)(OT + o * 80 + k * 16);
    } else {
      float* po = (float*)out + gbase;
#pragma unroll
      for (int k = 0; k < 8; k++)
        *(float4*)(po + k * 4) = *(const float4*)(OT + o * 144 + k * 16);
    }
  }
}

extern "C" void kernel_launch(void* const* d_in, const int* in_sizes, int n_in,
                              void* d_out, int out_size, void* d_ws, size_t ws_size,
                              hipStream_t stream) {
  const void* input   = d_in[0];
  const void* wq      = d_in[1];
  const void* q_scale = d_in[2];
  const void* q_bias  = d_in[3];
  const void* wkv     = d_in[4];
  const void* kv_scale= d_in[5];
  const void* kv_bias = d_in[6];
  const void* wp      = d_in[7];
  const void* p_scale = d_in[8];
  const void* p_bias  = d_in[9];

  char* w = (char*)d_ws;
  int*  flag = (int*)w;      w += 256;
  float* Spart = (float*)w;  w += (size_t)4096 * 1024 * 4;   // 16 MiB
  float* Zpart = (float*)w;  w += (size_t)8192 * ND * 4;     // 1 MiB
  float* ctx  = (float*)w;   w += (size_t)NB * ND * ND * 4;  // 32 KiB
  unsigned short* WqPh = (unsigned short*)w; w += (size_t)NC * NC * 2;
  unsigned short* WqPl = (unsigned short*)w; w += (size_t)NC * NC * 2;
  unsigned short* WpPh = (unsigned short*)w; w += (size_t)NC * NC * 2;
  unsigned short* WpPl = (unsigned short*)w; w += (size_t)NC * NC * 2;
  unsigned short* WkPh = (unsigned short*)w; w += (size_t)ND * NC * 2;
  unsigned short* WkPl = (unsigned short*)w; w += (size_t)ND * NC * 2;

  detect_kernel<<<1, 256, 0, stream>>>(input, flag);
  prep_weights<<<68, 256, 0, stream>>>(wq, wp, wkv, flag, WqPh, WqPl, WpPh, WpPl,
                                       WkPh, WkPl);
  kv_ctx<<<4096, 256, 0, stream>>>(input, WkPh, WkPl, kv_scale, kv_bias, flag,
                                   Spart, Zpart);
  ctx_redfin<<<256, 256, 0, stream>>>(Spart, Zpart, ctx);
  fused_main<<<4096, 256, 0, stream>>>(input, WqPh, WqPl, WpPh, WpPl,
                                       q_scale, q_bias, p_scale, p_bias,
                                       ctx, flag, (void*)d_out);
}

// Round 6
// 460.303 us; speedup vs baseline: 1.1302x; 1.1302x over previous
//
#include <hip/hip_runtime.h>
#include <hip/hip_bf16.h>

typedef __attribute__((ext_vector_type(8))) short bf16x8;
typedef __attribute__((ext_vector_type(4))) float f32x4;

#define NB 8
#define NC 256
#define ND 32
#define NN 16384
#define TILE_P 32

#define MFMA16(a, b, c) __builtin_amdgcn_mfma_f32_16x16x32_bf16((a), (b), (c), 0, 0, 0)

__device__ __forceinline__ float u2f(unsigned short u) {
  union { unsigned int i; float f; } v; v.i = ((unsigned int)u) << 16; return v.f;
}
__device__ __forceinline__ unsigned short f2u(float f) {
  union { float f; unsigned int i; } v; v.f = f;
  unsigned int x = v.i;
  return (unsigned short)((x + 0x7fffu + ((x >> 16) & 1u)) >> 16);  // RNE
}
__device__ __forceinline__ float ldg(const void* p, size_t i, int isbf) {
  return isbf ? u2f(((const unsigned short*)p)[i]) : ((const float*)p)[i];
}
// swizzled LDS addressing: row p (512B rows), byte col colb, 16B-block XOR swizzle.
__device__ __forceinline__ char* lds_at(char* base, int p, int colb) {
  return base + (p << 9) + (colb ^ ((p & 7) << 4));
}

// ---------------- dtype detect ----------------
__global__ __launch_bounds__(256) void detect_kernel(const void* __restrict__ x,
                                                     int* __restrict__ flag) {
  __shared__ int red[4];
  const unsigned int* w = (const unsigned int*)x;
  int cnt = 0;
  for (int i = threadIdx.x; i < 4096; i += 256) {
    unsigned int e = (w[i] >> 7) & 0xFFu;
    cnt += (e >= 100u && e <= 135u) ? 1 : 0;
  }
  for (int off = 32; off; off >>= 1) cnt += __shfl_xor(cnt, off, 64);
  if ((threadIdx.x & 63) == 0) red[threadIdx.x >> 6] = cnt;
  __syncthreads();
  if (threadIdx.x == 0)
    flag[0] = (red[0] + red[1] + red[2] + red[3] > 2048) ? 1 : 0;
}

// ---------------- prep: pack Wq/Wp/Wkv into per-lane MFMA A-fragment layout ----------------
// slot = (kt*NMB + mb)*64 + lane ; lane holds W[o = mb*16+(lane&15)][k = kt*32+8*(lane>>4)+e]
__global__ __launch_bounds__(256) void prep_weights(
    const void* __restrict__ wq, const void* __restrict__ wp,
    const void* __restrict__ wkv, const int* __restrict__ flag,
    unsigned short* __restrict__ WqPh, unsigned short* __restrict__ WqPl,
    unsigned short* __restrict__ WpPh, unsigned short* __restrict__ WpPl,
    unsigned short* __restrict__ WkPh, unsigned short* __restrict__ WkPl) {
  int isbf = flag[0];
  int idx = blockIdx.x * 256 + threadIdx.x;  // 17408 total
  const void* w;
  unsigned short *Ph, *Pl;
  int slot, o, k0;
  if (idx < 16384) {
    int mat = idx >> 13;
    slot = idx & 8191;
    int lane = slot & 63;
    int mbkt = slot >> 6;
    int mb = mbkt & 15, kt = mbkt >> 4;
    o = mb * 16 + (lane & 15);
    k0 = kt * 32 + (lane >> 4) * 8;
    w = mat ? wp : wq;
    Ph = mat ? WpPh : WqPh;
    Pl = mat ? WpPl : WqPl;
  } else {
    slot = idx - 16384;  // [0, 1024)
    int lane = slot & 63;
    int grp = slot >> 6;
    int mb = grp & 1, kt = grp >> 1;
    o = mb * 16 + (lane & 15);
    k0 = kt * 32 + (lane >> 4) * 8;
    w = wkv;
    Ph = WkPh;
    Pl = WkPl;
  }
  unsigned short h[8], lo[8];
#pragma unroll
  for (int e = 0; e < 8; e++) {
    float v = ldg(w, (size_t)o * NC + k0 + e, isbf);
    unsigned short hh = f2u(v);
    h[e] = hh;
    lo[e] = isbf ? (unsigned short)0 : f2u(v - u2f(hh));
  }
  uint4 ph, pl;
  ph.x = h[0] | ((unsigned)h[1] << 16);
  ph.y = h[2] | ((unsigned)h[3] << 16);
  ph.z = h[4] | ((unsigned)h[5] << 16);
  ph.w = h[6] | ((unsigned)h[7] << 16);
  pl.x = lo[0] | ((unsigned)lo[1] << 16);
  pl.y = lo[2] | ((unsigned)lo[3] << 16);
  pl.z = lo[4] | ((unsigned)lo[5] << 16);
  pl.w = lo[6] | ((unsigned)lo[7] << 16);
  *(uint4*)(Ph + (size_t)slot * 8) = ph;
  *(uint4*)(Pl + (size_t)slot * 8) = pl;
}

// ---------------- fused kv + ctx partials (templated, 128 px/block) ----------------
// Block = (b, 128-px chunk) = 4 sub-tiles of 32 px. Per sub-tile: kv = affine(Wkv@X)
// via MFMA -> E = exp(kv) (m==0, validated R4/R5) -> E/K hi/lo LDS transpose ->
// S-partial MFMAs accumulate in registers across sub-tiles. 1024 blocks, 4 blocks/CU.
template <int ISBF>
__global__ __launch_bounds__(256, 4) void kv_ctx(
    const void* __restrict__ x, const unsigned short* __restrict__ WkPh,
    const unsigned short* __restrict__ WkPl, const void* __restrict__ kv_scale,
    const void* __restrict__ kv_bias, const int* __restrict__ flag,
    float* __restrict__ Spart, float* __restrict__ Zpart) {
  __shared__ __align__(16) char pool[32768];
  if (flag[0] != ISBF) return;
  const int tid = threadIdx.x;
  const int bid = blockIdx.x;          // 1024 = 8 b x 128 chunks
  const int b = bid >> 7;
  const int nbase = (bid & 127) * 128;
  const int w = tid >> 6, l = tid & 63, g = l >> 4, cc = l & 15;
  const int mi = w >> 1, ni = w & 1;
  const f32x4 zero4 = {0.f, 0.f, 0.f, 0.f};
  const bf16x8* Ah = (const bf16x8*)WkPh;
  const bf16x8* Al = (const bf16x8*)WkPl;

  float scl[4], bia[4];
#pragma unroll
  for (int rr = 0; rr < 4; rr++) {
    int d = mi * 16 + 4 * g + rr;
    scl[rr] = ldg(kv_scale, d, ISBF);
    bia[rr] = ldg(kv_bias, d, ISBF);
  }

  f32x4 sacc = zero4;
  float zacc[4] = {0.f, 0.f, 0.f, 0.f};

  for (int st = 0; st < 4; st++) {
    const int n0 = nbase + st * 32;
    // ---- stage X sub-tile 32px x 256ch: hi at [0,16K), lo at [16K,32K) fp32 ----
    {
      const int c0 = (tid >> 3) * 8;
      const int pq = (tid & 7) * 4;
      unsigned short hi[8][4], lo[8][4];
      if (ISBF) {
        const unsigned short* xp =
            (const unsigned short*)x + ((size_t)(b * NC + c0)) * NN + n0 + pq;
#pragma unroll
        for (int i = 0; i < 8; i++) {
          ushort4 r = *(const ushort4*)(xp + (size_t)i * NN);
          hi[i][0] = r.x; hi[i][1] = r.y; hi[i][2] = r.z; hi[i][3] = r.w;
        }
      } else {
        const float* xp = (const float*)x + ((size_t)(b * NC + c0)) * NN + n0 + pq;
#pragma unroll
        for (int i = 0; i < 8; i++) {
          float4 v = *(const float4*)(xp + (size_t)i * NN);
          float vv[4] = {v.x, v.y, v.z, v.w};
#pragma unroll
          for (int j = 0; j < 4; j++) {
            unsigned short hh = f2u(vv[j]);
            hi[i][j] = hh;
            lo[i][j] = f2u(vv[j] - u2f(hh));
          }
        }
      }
#pragma unroll
      for (int j = 0; j < 4; j++) {
        int p = pq + j;
        uint4 wv;
        wv.x = hi[0][j] | ((unsigned)hi[1][j] << 16);
        wv.y = hi[2][j] | ((unsigned)hi[3][j] << 16);
        wv.z = hi[4][j] | ((unsigned)hi[5][j] << 16);
        wv.w = hi[6][j] | ((unsigned)hi[7][j] << 16);
        *(uint4*)lds_at(pool, p, c0 * 2) = wv;
        if (!ISBF) {
          uint4 wl2;
          wl2.x = lo[0][j] | ((unsigned)lo[1][j] << 16);
          wl2.y = lo[2][j] | ((unsigned)lo[3][j] << 16);
          wl2.z = lo[4][j] | ((unsigned)lo[5][j] << 16);
          wl2.w = lo[6][j] | ((unsigned)lo[7][j] << 16);
          *(uint4*)lds_at(pool + 16384, p, c0 * 2) = wl2;
        }
      }
    }
    __syncthreads();  // (A) staging complete

    // ---- kv GEMM quarter: wave (mi = d-half, ni = px-half) ----
    f32x4 acc = zero4;
#pragma unroll
    for (int kt = 0; kt < 8; kt++) {
      bf16x8 xb = *(const bf16x8*)lds_at(pool, ni * 16 + cc, kt * 64 + 16 * g);
      bf16x8 a = Ah[(kt * 2 + mi) * 64 + l];
      acc = MFMA16(a, xb, acc);
      if (!ISBF) {
        bf16x8 xl = *(const bf16x8*)lds_at(pool + 16384, ni * 16 + cc, kt * 64 + 16 * g);
        bf16x8 al = Al[(kt * 2 + mi) * 64 + l];
        acc = MFMA16(a, xl, acc);
        acc = MFMA16(al, xb, acc);
      }
    }

    // ---- affine + exp (m == 0) + hi/lo splits; accumulate Z ----
    unsigned short khv[4], klv[4], ehv[4], elv[4];
#pragma unroll
    for (int rr = 0; rr < 4; rr++) {
      float v = acc[rr] * scl[rr] + bia[rr];
      unsigned short kh = f2u(v);
      khv[rr] = kh;
      klv[rr] = f2u(v - u2f(kh));
      float e = __expf(v);
      zacc[rr] += e;
      unsigned short eh = f2u(e);
      ehv[rr] = eh;
      elv[rr] = f2u(e - u2f(eh));
    }
    __syncthreads();  // (B) staging reads done -> overlay E/K tiles

    // ---- write E/K tiles [32 d rows][32 px] bf16, 64B rows, per-row XOR swizzle ----
    {
      char* Eh = pool;
      char* El = pool + 2048;
      char* Kh = pool + 4096;
      char* Kl = pool + 6144;
      int px = ni * 16 + cc;
#pragma unroll
      for (int rr = 0; rr < 4; rr++) {
        int d = mi * 16 + 4 * g + rr;
        int off = d * 64 + ((px * 2) ^ ((d & 3) << 4));
        *(unsigned short*)(Eh + off) = ehv[rr];
        *(unsigned short*)(El + off) = elv[rr];
        *(unsigned short*)(Kh + off) = khv[rr];
        *(unsigned short*)(Kl + off) = klv[rr];
      }
    }
    __syncthreads();  // (C) E/K tiles complete

    // ---- S quarter accumulate: rows d (mi half) x cols e (ni half), K = 32 px ----
    {
      char* Eh = pool;
      char* El = pool + 2048;
      char* Kh = pool + 4096;
      char* Kl = pool + 6144;
      int ra = mi * 16 + cc;
      int rb = ni * 16 + cc;
      int ca = (16 * g) ^ ((ra & 3) << 4);
      int cb = (16 * g) ^ ((rb & 3) << 4);
      bf16x8 aEh = *(const bf16x8*)(Eh + ra * 64 + ca);
      bf16x8 aEl = *(const bf16x8*)(El + ra * 64 + ca);
      bf16x8 bKh = *(const bf16x8*)(Kh + rb * 64 + cb);
      bf16x8 bKl = *(const bf16x8*)(Kl + rb * 64 + cb);
      sacc = MFMA16(aEh, bKh, sacc);
      sacc = MFMA16(aEh, bKl, sacc);
      sacc = MFMA16(aEl, bKh, sacc);
    }
    __syncthreads();  // (D) E/K reads done before next stage overwrite
  }

  // ---- Z partial: reduce over the 16 px lanes (cc) of this wave ----
#pragma unroll
  for (int rr = 0; rr < 4; rr++) {
    zacc[rr] += __shfl_xor(zacc[rr], 1, 64);
    zacc[rr] += __shfl_xor(zacc[rr], 2, 64);
    zacc[rr] += __shfl_xor(zacc[rr], 4, 64);
    zacc[rr] += __shfl_xor(zacc[rr], 8, 64);
  }
  if (cc == 0) {
#pragma unroll
    for (int rr = 0; rr < 4; rr++)
      Zpart[((size_t)bid * 2 + ni) * ND + mi * 16 + 4 * g + rr] = zacc[rr];
  }
  // ---- S partial write ----
  {
    float* sp = Spart + (size_t)bid * 1024;
#pragma unroll
    for (int rr = 0; rr < 4; rr++)
      sp[(mi * 16 + 4 * g + rr) * 32 + ni * 16 + cc] = sacc[rr];
  }
}

// ---------------- reduce partials + divide -> ctx[b][d][e] ----------------
// block = (b, d): sums 128 S chunks (coalesced 128B rows) and 256 Z rows.
__global__ __launch_bounds__(256) void ctx_redfin(const float* __restrict__ Spart,
                                                  const float* __restrict__ Zpart,
                                                  float* __restrict__ ctx) {
  __shared__ float rs[256], rz[256];
  const int bid = blockIdx.x;  // 256 = 8 b x 32 d
  const int b = bid >> 5, d = bid & 31;
  const int t = threadIdx.x, e = t & 31, j = t >> 5;
  float s = 0.f;
  for (int c = j; c < 128; c += 8)
    s += Spart[((size_t)(b * 128 + c)) * 1024 + d * 32 + e];
  float z = Zpart[((size_t)(b * 256 + t)) * ND + d];
  rs[t] = s; rz[t] = z;
  __syncthreads();
  if (t < 128) { rs[t] += rs[t + 128]; rz[t] += rz[t + 128]; }
  __syncthreads();
  if (t < 64) { rs[t] += rs[t + 64]; rz[t] += rz[t + 64]; }
  __syncthreads();
  if (t < 32) {
    float ss = rs[t] + rs[t + 32];
    float zz = rz[t] + rz[t + 32];
    zz += __shfl_xor(zz, 1, 64);
    zz += __shfl_xor(zz, 2, 64);
    zz += __shfl_xor(zz, 4, 64);
    zz += __shfl_xor(zz, 8, 64);
    zz += __shfl_xor(zz, 16, 64);
    ctx[((size_t)b * ND + d) * ND + t] = ss / zz;
  }
}

// ---------------- fused: q GEMM -> softmax(D) -> ctx matvec -> relu -> out GEMM ----------------
// R3-proven template structure (169us benched). fp32 terms: GEMM1 6, ctx 3, GEMM2 6
// (exactly R5's numerics, absmax 0.00195 verified).
template <int ISBF>
__global__ __launch_bounds__(256, 2) void fused_main(
    const void* __restrict__ x,
    const unsigned short* __restrict__ WqPh, const unsigned short* __restrict__ WqPl,
    const unsigned short* __restrict__ WpPh, const unsigned short* __restrict__ WpPl,
    const void* __restrict__ q_scale, const void* __restrict__ q_bias,
    const void* __restrict__ p_scale, const void* __restrict__ p_bias,
    const float* __restrict__ ctx, const int* __restrict__ flag,
    void* __restrict__ out) {
  constexpr int XT_O = 0;
  constexpr int XTL_O = 16384;                    // fp32 only
  constexpr int SMH_O = ISBF ? 16384 : 32768;
  constexpr int SML_O = ISBF ? 32768 : 49152;
  constexpr int YTH_O = 0;                        // overlays XT
  constexpr int YTL_O = 16384;                    // overlays XTL (fp32)
  constexpr int OT_O = ISBF ? 16384 : 32768;      // overlays SM tiles
  constexpr int OT_STR = ISBF ? 88 : 132;
  constexpr int POOL = ISBF ? 49152 : 69632;
  __shared__ __align__(16) char pool[POOL];
  __shared__ float qs_l[NC], qb_l[NC], ps_l[NC], pb_l[NC];
  if (flag[0] != ISBF) return;
  const int tid = threadIdx.x;
  const int b = blockIdx.x >> 9;
  const int n0 = (blockIdx.x & 511) * TILE_P;
  const int w = tid >> 6;
  const int l = tid & 63;
  const int g = l >> 4;
  const int cc = l & 15;
  const f32x4 zero4 = {0.f, 0.f, 0.f, 0.f};

  qs_l[tid] = ldg(q_scale, tid, ISBF);
  qb_l[tid] = ldg(q_bias, tid, ISBF);
  ps_l[tid] = ldg(p_scale, tid, ISBF);
  pb_l[tid] = ldg(p_bias, tid, ISBF);

  // ctx A-fragments: A[m=e][k=d] = ctx[d][e], hi/lo
  bf16x8 cAh[2], cAl[2];
  {
    const float* cb = ctx + (size_t)b * ND * ND;
#pragma unroll
    for (int mp = 0; mp < 2; mp++) {
      bf16x8 ah, al;
#pragma unroll
      for (int el = 0; el < 8; el++) {
        float v = cb[(8 * g + el) * ND + 16 * mp + cc];
        unsigned short hh = f2u(v);
        ah[el] = (short)hh;
        al[el] = (short)f2u(v - u2f(hh));
      }
      cAh[mp] = ah; cAl[mp] = al;
    }
  }

  // ---- stage X tile: XT[p(32)][c(256)] bf16 hi (+lo fp32 mode) ----
  {
    const int c0 = (tid >> 3) * 8;
    const int pq = (tid & 7) * 4;
    unsigned short hi[8][4], lo[8][4];
    if (ISBF) {
      const unsigned short* xp =
          (const unsigned short*)x + ((size_t)(b * NC + c0)) * NN + n0 + pq;
#pragma unroll
      for (int i = 0; i < 8; i++) {
        ushort4 r = *(const ushort4*)(xp + (size_t)i * NN);
        hi[i][0] = r.x; hi[i][1] = r.y; hi[i][2] = r.z; hi[i][3] = r.w;
      }
    } else {
      const float* xp = (const float*)x + ((size_t)(b * NC + c0)) * NN + n0 + pq;
#pragma unroll
      for (int i = 0; i < 8; i++) {
        float4 v = *(const float4*)(xp + (size_t)i * NN);
        float vv[4] = {v.x, v.y, v.z, v.w};
#pragma unroll
        for (int j = 0; j < 4; j++) {
          unsigned short hh = f2u(vv[j]);
          hi[i][j] = hh;
          lo[i][j] = f2u(vv[j] - u2f(hh));
        }
      }
    }
#pragma unroll
    for (int j = 0; j < 4; j++) {
      int p = pq + j;
      uint4 wv;
      wv.x = hi[0][j] | ((unsigned)hi[1][j] << 16);
      wv.y = hi[2][j] | ((unsigned)hi[3][j] << 16);
      wv.z = hi[4][j] | ((unsigned)hi[5][j] << 16);
      wv.w = hi[6][j] | ((unsigned)hi[7][j] << 16);
      *(uint4*)lds_at(pool + XT_O, p, c0 * 2) = wv;
      if (!ISBF) {
        uint4 wl2;
        wl2.x = lo[0][j] | ((unsigned)lo[1][j] << 16);
        wl2.y = lo[2][j] | ((unsigned)lo[3][j] << 16);
        wl2.z = lo[4][j] | ((unsigned)lo[5][j] << 16);
        wl2.w = lo[6][j] | ((unsigned)lo[7][j] << 16);
        *(uint4*)lds_at(pool + XTL_O, p, c0 * 2) = wl2;
      }
    }
  }
  __syncthreads();

  // ---- GEMM1: q = Wq @ x (fp32: 6-term) ----
  f32x4 acc[4][2];
#pragma unroll
  for (int mi = 0; mi < 4; mi++) { acc[mi][0] = zero4; acc[mi][1] = zero4; }
  {
    const bf16x8* Aq = (const bf16x8*)WqPh;
    const bf16x8* Aql = (const bf16x8*)WqPl;
#pragma unroll
    for (int kt = 0; kt < 8; kt++) {
      bf16x8 xb0 = *(const bf16x8*)lds_at(pool + XT_O, cc, kt * 64 + 16 * g);
      bf16x8 xb1 = *(const bf16x8*)lds_at(pool + XT_O, 16 + cc, kt * 64 + 16 * g);
      bf16x8 av[4];
#pragma unroll
      for (int mi = 0; mi < 4; mi++) av[mi] = Aq[(kt * 16 + w * 4 + mi) * 64 + l];
#pragma unroll
      for (int mi = 0; mi < 4; mi++) {
        acc[mi][0] = MFMA16(av[mi], xb0, acc[mi][0]);
        acc[mi][1] = MFMA16(av[mi], xb1, acc[mi][1]);
      }
      if (!ISBF) {
        bf16x8 xl0 = *(const bf16x8*)lds_at(pool + XTL_O, cc, kt * 64 + 16 * g);
        bf16x8 xl1 = *(const bf16x8*)lds_at(pool + XTL_O, 16 + cc, kt * 64 + 16 * g);
#pragma unroll
        for (int mi = 0; mi < 4; mi++) {
          bf16x8 al2 = Aql[(kt * 16 + w * 4 + mi) * 64 + l];
          acc[mi][0] = MFMA16(av[mi], xl0, acc[mi][0]);
          acc[mi][1] = MFMA16(av[mi], xl1, acc[mi][1]);
          acc[mi][0] = MFMA16(al2, xb0, acc[mi][0]);
          acc[mi][1] = MFMA16(al2, xb1, acc[mi][1]);
        }
      }
    }
  }

  // ---- softmax over D per (head,pixel); E hi/lo -> SM tiles ----
  float inv_s[2][2];
#pragma unroll
  for (int hp = 0; hp < 2; hp++) {
#pragma unroll
    for (int ni = 0; ni < 2; ni++) {
      float e8[8];
      float mx = -3.0e38f;
#pragma unroll
      for (int mi2 = 0; mi2 < 2; mi2++) {
#pragma unroll
        for (int r = 0; r < 4; r++) {
          int o = w * 64 + (2 * hp + mi2) * 16 + 4 * g + r;
          float v = acc[2 * hp + mi2][ni][r] * qs_l[o] + qb_l[o];
          e8[mi2 * 4 + r] = v;
          mx = fmaxf(mx, v);
        }
      }
      mx = fmaxf(mx, __shfl_xor(mx, 16, 64));
      mx = fmaxf(mx, __shfl_xor(mx, 32, 64));
      float s = 0.f;
#pragma unroll
      for (int i2 = 0; i2 < 8; i2++) { e8[i2] = __expf(e8[i2] - mx); s += e8[i2]; }
      s += __shfl_xor(s, 16, 64);
      s += __shfl_xor(s, 32, 64);
      inv_s[hp][ni] = 1.f / s;
      int p = ni * 16 + cc;
#pragma unroll
      for (int mi2 = 0; mi2 < 2; mi2++) {
        int colb = (w * 64 + (2 * hp + mi2) * 16 + 4 * g) * 2;
        unsigned short h[4], lo2[4];
#pragma unroll
        for (int r = 0; r < 4; r++) {
          float ev = e8[mi2 * 4 + r];
          unsigned short hh = f2u(ev);
          h[r] = hh;
          lo2[r] = f2u(ev - u2f(hh));
        }
        uint2 wh, wl2;
        wh.x = h[0] | ((unsigned)h[1] << 16);
        wh.y = h[2] | ((unsigned)h[3] << 16);
        wl2.x = lo2[0] | ((unsigned)lo2[1] << 16);
        wl2.y = lo2[2] | ((unsigned)lo2[3] << 16);
        *(uint2*)lds_at(pool + SMH_O, p, colb) = wh;
        *(uint2*)lds_at(pool + SML_O, p, colb) = wl2;
      }
    }
  }
  __syncthreads();  // (1) all XT reads done; SM tiles complete

  // ---- ctx GEMM: att = ctx^T @ E (3-term), /s, relu, hi/lo -> YT tiles ----
#pragma unroll
  for (int hp = 0; hp < 2; hp++) {
    f32x4 cacc[2][2];
#pragma unroll
    for (int mp = 0; mp < 2; mp++) { cacc[mp][0] = zero4; cacc[mp][1] = zero4; }
#pragma unroll
    for (int ni = 0; ni < 2; ni++) {
      int p = ni * 16 + cc;
      int colb = ((2 * w + hp) * 32 + 8 * g) * 2;
      bf16x8 bh = *(const bf16x8*)lds_at(pool + SMH_O, p, colb);
      bf16x8 bl = *(const bf16x8*)lds_at(pool + SML_O, p, colb);
#pragma unroll
      for (int mp = 0; mp < 2; mp++) {
        cacc[mp][ni] = MFMA16(cAh[mp], bh, cacc[mp][ni]);
        cacc[mp][ni] = MFMA16(cAh[mp], bl, cacc[mp][ni]);
        cacc[mp][ni] = MFMA16(cAl[mp], bh, cacc[mp][ni]);
      }
    }
#pragma unroll
    for (int mp = 0; mp < 2; mp++) {
#pragma unroll
      for (int ni = 0; ni < 2; ni++) {
        int p = ni * 16 + cc;
        float iv = inv_s[hp][ni];
        unsigned short h[4], lo2[4];
#pragma unroll
        for (int r = 0; r < 4; r++) {
          float y = fmaxf(cacc[mp][ni][r] * iv, 0.f);
          unsigned short hh = f2u(y);
          h[r] = hh;
          lo2[r] = f2u(y - u2f(hh));
        }
        int colb = ((2 * w + hp) * 32 + mp * 16 + 4 * g) * 2;
        uint2 wh;
        wh.x = h[0] | ((unsigned)h[1] << 16);
        wh.y = h[2] | ((unsigned)h[3] << 16);
        *(uint2*)lds_at(pool + YTH_O, p, colb) = wh;
        uint2 wl2;
        wl2.x = lo2[0] | ((unsigned)lo2[1] << 16);
        wl2.y = lo2[2] | ((unsigned)lo2[3] << 16);
        *(uint2*)lds_at(pool + YTL_O, p, colb) = wl2;
      }
    }
  }
  __syncthreads();  // (2) YT tiles complete

  // ---- GEMM2: out = Wp @ relu(att) (fp32: 6-term, bf16: 4-term) ----
  f32x4 oacc[4][2];
#pragma unroll
  for (int mi = 0; mi < 4; mi++) { oacc[mi][0] = zero4; oacc[mi][1] = zero4; }
  {
    const bf16x8* Ap = (const bf16x8*)WpPh;
    const bf16x8* Apl = (const bf16x8*)WpPl;
#pragma unroll
    for (int kt = 0; kt < 8; kt++) {
      bf16x8 yh0 = *(const bf16x8*)lds_at(pool + YTH_O, cc, kt * 64 + 16 * g);
      bf16x8 yh1 = *(const bf16x8*)lds_at(pool + YTH_O, 16 + cc, kt * 64 + 16 * g);
      bf16x8 yl0 = *(const bf16x8*)lds_at(pool + YTL_O, cc, kt * 64 + 16 * g);
      bf16x8 yl1 = *(const bf16x8*)lds_at(pool + YTL_O, 16 + cc, kt * 64 + 16 * g);
      bf16x8 av[4];
#pragma unroll
      for (int mi = 0; mi < 4; mi++) av[mi] = Ap[(kt * 16 + w * 4 + mi) * 64 + l];
#pragma unroll
      for (int mi = 0; mi < 4; mi++) {
        oacc[mi][0] = MFMA16(av[mi], yh0, oacc[mi][0]);
        oacc[mi][1] = MFMA16(av[mi], yh1, oacc[mi][1]);
        oacc[mi][0] = MFMA16(av[mi], yl0, oacc[mi][0]);
        oacc[mi][1] = MFMA16(av[mi], yl1, oacc[mi][1]);
      }
      if (!ISBF) {
#pragma unroll
        for (int mi = 0; mi < 4; mi++) {
          bf16x8 al2 = Apl[(kt * 16 + w * 4 + mi) * 64 + l];
          oacc[mi][0] = MFMA16(al2, yh0, oacc[mi][0]);
          oacc[mi][1] = MFMA16(al2, yh1, oacc[mi][1]);
        }
      }
    }
  }

  // ---- epilogue: affine -> OT (channel-major) -> coalesced global store ----
  {
    char* OT = pool + OT_O;
#pragma unroll
    for (int mi = 0; mi < 4; mi++) {
#pragma unroll
      for (int ni = 0; ni < 2; ni++) {
#pragma unroll
        for (int r = 0; r < 4; r++) {
          int o = w * 64 + mi * 16 + 4 * g + r;
          float v = oacc[mi][ni][r] * ps_l[o] + pb_l[o];
          int p = ni * 16 + cc;
          if (ISBF)
            *(unsigned short*)(OT + o * OT_STR + p * 2) = f2u(v);
          else
            *(float*)(OT + o * OT_STR + p * 4) = v;
        }
      }
    }
  }
  __syncthreads();  // (3) OT complete
  {
    char* OT = pool + OT_O;
    int o = tid;
    size_t gbase = ((size_t)(b * NC + o)) * NN + n0;
    if (ISBF) {
      unsigned short* po = (unsigned short*)out + gbase;
#pragma unroll
      for (int k = 0; k < 4; k++) {
        uint2 a = *(const uint2*)(OT + o * OT_STR + k * 16);
        uint2 b2 = *(const uint2*)(OT + o * OT_STR + k * 16 + 8);
        *(uint4*)(po + k * 8) = make_uint4(a.x, a.y, b2.x, b2.y);
      }
    } else {
      float* po = (float*)out + gbase;
#pragma unroll
      for (int k = 0; k < 8; k++) {
        float4 v;
        v.x = *(const float*)(OT + o * OT_STR + (k * 4 + 0) * 4);
        v.y = *(const float*)(OT + o * OT_STR + (k * 4 + 1) * 4);
        v.z = *(const float*)(OT + o * OT_STR + (k * 4 + 2) * 4);
        v.w = *(const float*)(OT + o * OT_STR + (k * 4 + 3) * 4);
        *(float4*)(po + k * 4) = v;
      }
    }
  }
}

extern "C" void kernel_launch(void* const* d_in, const int* in_sizes, int n_in,
                              void* d_out, int out_size, void* d_ws, size_t ws_size,
                              hipStream_t stream) {
  const void* input   = d_in[0];
  const void* wq      = d_in[1];
  const void* q_scale = d_in[2];
  const void* q_bias  = d_in[3];
  const void* wkv     = d_in[4];
  const void* kv_scale= d_in[5];
  const void* kv_bias = d_in[6];
  const void* wp      = d_in[7];
  const void* p_scale = d_in[8];
  const void* p_bias  = d_in[9];

  char* w = (char*)d_ws;
  int*  flag = (int*)w;      w += 256;
  float* Spart = (float*)w;  w += (size_t)1024 * 1024 * 4;   // 4 MiB
  float* Zpart = (float*)w;  w += (size_t)2048 * ND * 4;     // 256 KiB
  float* ctx  = (float*)w;   w += (size_t)NB * ND * ND * 4;  // 32 KiB
  unsigned short* WqPh = (unsigned short*)w; w += (size_t)NC * NC * 2;
  unsigned short* WqPl = (unsigned short*)w; w += (size_t)NC * NC * 2;
  unsigned short* WpPh = (unsigned short*)w; w += (size_t)NC * NC * 2;
  unsigned short* WpPl = (unsigned short*)w; w += (size_t)NC * NC * 2;
  unsigned short* WkPh = (unsigned short*)w; w += (size_t)ND * NC * 2;
  unsigned short* WkPl = (unsigned short*)w; w += (size_t)ND * NC * 2;

  detect_kernel<<<1, 256, 0, stream>>>(input, flag);
  prep_weights<<<68, 256, 0, stream>>>(wq, wp, wkv, flag, WqPh, WqPl, WpPh, WpPl,
                                       WkPh, WkPl);
  kv_ctx<1><<<1024, 256, 0, stream>>>(input, WkPh, WkPl, kv_scale, kv_bias, flag,
                                      Spart, Zpart);
  kv_ctx<0><<<1024, 256, 0, stream>>>(input, WkPh, WkPl, kv_scale, kv_bias, flag,
                                      Spart, Zpart);
  ctx_redfin<<<256, 256, 0, stream>>>(Spart, Zpart, ctx);
  fused_main<1><<<4096, 256, 0, stream>>>(input, WqPh, WqPl, WpPh, WpPl,
                                          q_scale, q_bias, p_scale, p_bias,
                                          ctx, flag, (void*)d_out);
  fused_main<0><<<4096, 256, 0, stream>>>(input, WqPh, WqPl, WpPh, WpPl,
                                          q_scale, q_bias, p_scale, p_bias,
                                          ctx, flag, (void*)d_out);
}

// Round 9
// 447.790 us; speedup vs baseline: 1.1618x; 1.0279x over previous
//
#include <hip/hip_runtime.h>
#include <hip/hip_bf16.h>

typedef __attribute__((ext_vector_type(8))) short bf16x8;
typedef __attribute__((ext_vector_type(4))) float f32x4;

#define NB 8
#define NC 256
#define ND 32
#define NN 16384
#define TILE_P 32

#define MFMA16(a, b, c) __builtin_amdgcn_mfma_f32_16x16x32_bf16((a), (b), (c), 0, 0, 0)

__device__ __forceinline__ float u2f(unsigned short u) {
  union { unsigned int i; float f; } v; v.i = ((unsigned int)u) << 16; return v.f;
}
__device__ __forceinline__ unsigned short f2u(float f) {
  union { float f; unsigned int i; } v; v.f = f;
  unsigned int x = v.i;
  return (unsigned short)((x + 0x7fffu + ((x >> 16) & 1u)) >> 16);  // RNE
}
__device__ __forceinline__ float ldg(const void* p, size_t i, int isbf) {
  return isbf ? u2f(((const unsigned short*)p)[i]) : ((const float*)p)[i];
}
// swizzled LDS addressing: row p (512B rows), byte col colb, 16B-block XOR swizzle.
__device__ __forceinline__ char* lds_at(char* base, int p, int colb) {
  return base + (p << 9) + (colb ^ ((p & 7) << 4));
}

// ---------------- dtype detect ----------------
__global__ __launch_bounds__(256) void detect_kernel(const void* __restrict__ x,
                                                     int* __restrict__ flag) {
  __shared__ int red[4];
  const unsigned int* w = (const unsigned int*)x;
  int cnt = 0;
  for (int i = threadIdx.x; i < 4096; i += 256) {
    unsigned int e = (w[i] >> 7) & 0xFFu;
    cnt += (e >= 100u && e <= 135u) ? 1 : 0;
  }
  for (int off = 32; off; off >>= 1) cnt += __shfl_xor(cnt, off, 64);
  if ((threadIdx.x & 63) == 0) red[threadIdx.x >> 6] = cnt;
  __syncthreads();
  if (threadIdx.x == 0)
    flag[0] = (red[0] + red[1] + red[2] + red[3] > 2048) ? 1 : 0;
}

// ---------------- prep: pack Wq/Wp/Wkv into per-lane MFMA A-fragment layout ----------------
// slot = (kt*NMB + mb)*64 + lane ; lane holds W[o = mb*16+(lane&15)][k = kt*32+8*(lane>>4)+e]
__global__ __launch_bounds__(256) void prep_weights(
    const void* __restrict__ wq, const void* __restrict__ wp,
    const void* __restrict__ wkv, const int* __restrict__ flag,
    unsigned short* __restrict__ WqPh, unsigned short* __restrict__ WqPl,
    unsigned short* __restrict__ WpPh, unsigned short* __restrict__ WpPl,
    unsigned short* __restrict__ WkPh, unsigned short* __restrict__ WkPl) {
  int isbf = flag[0];
  int idx = blockIdx.x * 256 + threadIdx.x;  // 17408 total
  const void* w;
  unsigned short *Ph, *Pl;
  int slot, o, k0;
  if (idx < 16384) {
    int mat = idx >> 13;
    slot = idx & 8191;
    int lane = slot & 63;
    int mbkt = slot >> 6;
    int mb = mbkt & 15, kt = mbkt >> 4;
    o = mb * 16 + (lane & 15);
    k0 = kt * 32 + (lane >> 4) * 8;
    w = mat ? wp : wq;
    Ph = mat ? WpPh : WqPh;
    Pl = mat ? WpPl : WqPl;
  } else {
    slot = idx - 16384;  // [0, 1024)
    int lane = slot & 63;
    int grp = slot >> 6;
    int mb = grp & 1, kt = grp >> 1;
    o = mb * 16 + (lane & 15);
    k0 = kt * 32 + (lane >> 4) * 8;
    w = wkv;
    Ph = WkPh;
    Pl = WkPl;
  }
  unsigned short h[8], lo[8];
#pragma unroll
  for (int e = 0; e < 8; e++) {
    float v = ldg(w, (size_t)o * NC + k0 + e, isbf);
    unsigned short hh = f2u(v);
    h[e] = hh;
    lo[e] = isbf ? (unsigned short)0 : f2u(v - u2f(hh));
  }
  uint4 ph, pl;
  ph.x = h[0] | ((unsigned)h[1] << 16);
  ph.y = h[2] | ((unsigned)h[3] << 16);
  ph.z = h[4] | ((unsigned)h[5] << 16);
  ph.w = h[6] | ((unsigned)h[7] << 16);
  pl.x = lo[0] | ((unsigned)lo[1] << 16);
  pl.y = lo[2] | ((unsigned)lo[3] << 16);
  pl.z = lo[4] | ((unsigned)lo[5] << 16);
  pl.w = lo[6] | ((unsigned)lo[7] << 16);
  *(uint4*)(Ph + (size_t)slot * 8) = ph;
  *(uint4*)(Pl + (size_t)slot * 8) = pl;
}

// ---------------- fused kv + ctx partials v2: no X staging ----------------
// Block = (b, 128-px chunk) = 4 sub-tiles of 32 px. B-fragments for the kv MFMA are
// loaded DIRECTLY from global (lane l: px = l&15 within its half, k = kt*32+8*(l>>4)+e;
// per-e instruction = 16 lanes x 4B consecutive = full 64B lines). fp32 lo-fragment is
// derived in-register. Only the 8KB E/K transpose tile remains in LDS -> 2 barriers
// per sub-tile instead of 4.
template <int ISBF>
__global__ __launch_bounds__(256, 4) void kv_ctx(
    const void* __restrict__ x, const unsigned short* __restrict__ WkPh,
    const unsigned short* __restrict__ WkPl, const void* __restrict__ kv_scale,
    const void* __restrict__ kv_bias, const int* __restrict__ flag,
    float* __restrict__ Spart, float* __restrict__ Zpart) {
  __shared__ __align__(16) char pool[8192];
  if (flag[0] != ISBF) return;
  const int tid = threadIdx.x;
  const int bid = blockIdx.x;          // 1024 = 8 b x 128 chunks
  const int b = bid >> 7;
  const int nbase = (bid & 127) * 128;
  const int w = tid >> 6, l = tid & 63, g = l >> 4, cc = l & 15;
  const int mi = w >> 1, ni = w & 1;
  const f32x4 zero4 = {0.f, 0.f, 0.f, 0.f};
  const bf16x8* Ah = (const bf16x8*)WkPh;
  const bf16x8* Al = (const bf16x8*)WkPl;

  float scl[4], bia[4];
#pragma unroll
  for (int rr = 0; rr < 4; rr++) {
    int d = mi * 16 + 4 * g + rr;
    scl[rr] = ldg(kv_scale, d, ISBF);
    bia[rr] = ldg(kv_bias, d, ISBF);
  }

  f32x4 sacc = zero4;
  float zacc[4] = {0.f, 0.f, 0.f, 0.f};

  char* Eh = pool;
  char* El = pool + 2048;
  char* Kh = pool + 4096;
  char* Kl = pool + 6144;

  for (int st = 0; st < 4; st++) {
    const int px = nbase + st * 32 + ni * 16 + cc;

    // ---- kv GEMM: B-fragments direct from global; A from packed weights ----
    f32x4 acc = zero4;
    if (ISBF) {
      const unsigned short* xb =
          (const unsigned short*)x + (size_t)b * NC * NN + px;
#pragma unroll
      for (int kt = 0; kt < 8; kt++) {
        bf16x8 xh;
#pragma unroll
        for (int e = 0; e < 8; e++)
          xh[e] = (short)xb[(size_t)(kt * 32 + 8 * g + e) * NN];
        acc = MFMA16(Ah[(kt * 2 + mi) * 64 + l], xh, acc);
      }
    } else {
      const float* xb = (const float*)x + (size_t)b * NC * NN + px;
#pragma unroll
      for (int kt = 0; kt < 8; kt++) {
        bf16x8 xh, xl;
#pragma unroll
        for (int e = 0; e < 8; e++) {
          float v = xb[(size_t)(kt * 32 + 8 * g + e) * NN];
          unsigned short hh = f2u(v);
          xh[e] = (short)hh;
          xl[e] = (short)f2u(v - u2f(hh));
        }
        bf16x8 a = Ah[(kt * 2 + mi) * 64 + l];
        bf16x8 al = Al[(kt * 2 + mi) * 64 + l];
        acc = MFMA16(a, xh, acc);
        acc = MFMA16(a, xl, acc);
        acc = MFMA16(al, xh, acc);
      }
    }

    // ---- affine + exp (m == 0) + hi/lo splits; accumulate Z ----
    unsigned short khv[4], klv[4], ehv[4], elv[4];
#pragma unroll
    for (int rr = 0; rr < 4; rr++) {
      float v = acc[rr] * scl[rr] + bia[rr];
      unsigned short kh = f2u(v);
      khv[rr] = kh;
      klv[rr] = f2u(v - u2f(kh));
      float e = __expf(v);
      zacc[rr] += e;
      unsigned short eh = f2u(e);
      ehv[rr] = eh;
      elv[rr] = f2u(e - u2f(eh));
    }

    // ---- write E/K tiles [32 d rows][32 px] bf16, 64B rows, per-row XOR swizzle ----
    {
      int pxl = ni * 16 + cc;
#pragma unroll
      for (int rr = 0; rr < 4; rr++) {
        int d = mi * 16 + 4 * g + rr;
        int off = d * 64 + ((pxl * 2) ^ ((d & 3) << 4));
        *(unsigned short*)(Eh + off) = ehv[rr];
        *(unsigned short*)(El + off) = elv[rr];
        *(unsigned short*)(Kh + off) = khv[rr];
        *(unsigned short*)(Kl + off) = klv[rr];
      }
    }
    __syncthreads();  // (1) E/K tiles complete

    // ---- S quarter accumulate: rows d (mi half) x cols e (ni half), K = 32 px ----
    {
      int ra = mi * 16 + cc;
      int rb = ni * 16 + cc;
      int ca = (16 * g) ^ ((ra & 3) << 4);
      int cb = (16 * g) ^ ((rb & 3) << 4);
      bf16x8 aEh = *(const bf16x8*)(Eh + ra * 64 + ca);
      bf16x8 aEl = *(const bf16x8*)(El + ra * 64 + ca);
      bf16x8 bKh = *(const bf16x8*)(Kh + rb * 64 + cb);
      bf16x8 bKl = *(const bf16x8*)(Kl + rb * 64 + cb);
      sacc = MFMA16(aEh, bKh, sacc);
      sacc = MFMA16(aEh, bKl, sacc);
      sacc = MFMA16(aEl, bKh, sacc);
    }
    __syncthreads();  // (2) E/K reads done before next sub-tile overwrite
  }

  // ---- Z partial: reduce over the 16 px lanes (cc) of this wave ----
#pragma unroll
  for (int rr = 0; rr < 4; rr++) {
    zacc[rr] += __shfl_xor(zacc[rr], 1, 64);
    zacc[rr] += __shfl_xor(zacc[rr], 2, 64);
    zacc[rr] += __shfl_xor(zacc[rr], 4, 64);
    zacc[rr] += __shfl_xor(zacc[rr], 8, 64);
  }
  if (cc == 0) {
#pragma unroll
    for (int rr = 0; rr < 4; rr++)
      Zpart[((size_t)bid * 2 + ni) * ND + mi * 16 + 4 * g + rr] = zacc[rr];
  }
  // ---- S partial write ----
  {
    float* sp = Spart + (size_t)bid * 1024;
#pragma unroll
    for (int rr = 0; rr < 4; rr++)
      sp[(mi * 16 + 4 * g + rr) * 32 + ni * 16 + cc] = sacc[rr];
  }
}

// ---------------- reduce partials + divide -> ctx[b][d][e] ----------------
// block = (b, d): sums 128 S chunks (coalesced 128B rows) and 256 Z rows.
__global__ __launch_bounds__(256) void ctx_redfin(const float* __restrict__ Spart,
                                                  const float* __restrict__ Zpart,
                                                  float* __restrict__ ctx) {
  __shared__ float rs[256], rz[256];
  const int bid = blockIdx.x;  // 256 = 8 b x 32 d
  const int b = bid >> 5, d = bid & 31;
  const int t = threadIdx.x, e = t & 31, j = t >> 5;
  float s = 0.f;
  for (int c = j; c < 128; c += 8)
    s += Spart[((size_t)(b * 128 + c)) * 1024 + d * 32 + e];
  float z = Zpart[((size_t)(b * 256 + t)) * ND + d];
  rs[t] = s; rz[t] = z;
  __syncthreads();
  if (t < 128) { rs[t] += rs[t + 128]; rz[t] += rz[t + 128]; }
  __syncthreads();
  if (t < 64) { rs[t] += rs[t + 64]; rz[t] += rz[t + 64]; }
  __syncthreads();
  if (t < 32) {
    float ss = rs[t] + rs[t + 32];
    float zz = rz[t] + rz[t + 32];
    zz += __shfl_xor(zz, 1, 64);
    zz += __shfl_xor(zz, 2, 64);
    zz += __shfl_xor(zz, 4, 64);
    zz += __shfl_xor(zz, 8, 64);
    zz += __shfl_xor(zz, 16, 64);
    ctx[((size_t)b * ND + d) * ND + t] = ss / zz;
  }
}

// ---------------- fused: q GEMM -> softmax(D) -> ctx matvec -> relu -> out GEMM ----------------
// EXACT byte-faithful revert to the R3-benched kernel (169us, absmax 0.00195):
// GEMM1 6-term fp32, ctx 4-term fp32, Y hi(+lo fp32), GEMM2 6-term fp32,
// OT stride 88/144, float4 epilogue loads.
template <int ISBF>
__global__ __launch_bounds__(256, 2) void fused_main(
    const void* __restrict__ x,
    const unsigned short* __restrict__ WqPh, const unsigned short* __restrict__ WqPl,
    const unsigned short* __restrict__ WpPh, const unsigned short* __restrict__ WpPl,
    const void* __restrict__ q_scale, const void* __restrict__ q_bias,
    const void* __restrict__ p_scale, const void* __restrict__ p_bias,
    const float* __restrict__ ctx, const int* __restrict__ flag,
    void* __restrict__ out) {
  constexpr int XT_O = 0;
  constexpr int XTL_O = 16384;                    // fp32 only
  constexpr int SMH_O = ISBF ? 16384 : 32768;
  constexpr int SML_O = ISBF ? 32768 : 49152;
  constexpr int YTH_O = 0;                        // overlays XT
  constexpr int YTL_O = 16384;                    // fp32 only, overlays XTL
  constexpr int OT_O = ISBF ? 16384 : 32768;      // overlays SM tiles
  constexpr int OT_STR = ISBF ? 88 : 144;
  constexpr int POOL = ISBF ? 49152 : 69632;
  __shared__ __align__(16) char pool[POOL];
  __shared__ float qs_l[NC], qb_l[NC], ps_l[NC], pb_l[NC];
  if (flag[0] != ISBF) return;
  const int tid = threadIdx.x;
  const int b = blockIdx.x >> 9;
  const int n0 = (blockIdx.x & 511) * TILE_P;
  const int w = tid >> 6;
  const int l = tid & 63;
  const int g = l >> 4;
  const int cc = l & 15;
  const f32x4 zero4 = {0.f, 0.f, 0.f, 0.f};

  qs_l[tid] = ldg(q_scale, tid, ISBF);
  qb_l[tid] = ldg(q_bias, tid, ISBF);
  ps_l[tid] = ldg(p_scale, tid, ISBF);
  pb_l[tid] = ldg(p_bias, tid, ISBF);

  // ctx A-fragments: A[m=e][k=d] = ctx[d][e], hi/lo
  bf16x8 cAh[2], cAl[2];
  {
    const float* cb = ctx + (size_t)b * ND * ND;
#pragma unroll
    for (int mp = 0; mp < 2; mp++) {
      bf16x8 ah, al;
#pragma unroll
      for (int el = 0; el < 8; el++) {
        float v = cb[(8 * g + el) * ND + 16 * mp + cc];
        unsigned short hh = f2u(v);
        ah[el] = (short)hh;
        al[el] = (short)f2u(v - u2f(hh));
      }
      cAh[mp] = ah; cAl[mp] = al;
    }
  }

  // ---- stage X tile: XT[p(32)][c(256)] bf16 hi (+lo fp32 mode) ----
  {
    const int c0 = (tid >> 3) * 8;
    const int pq = (tid & 7) * 4;
    unsigned short hi[8][4], lo[8][4];
    if (ISBF) {
      const unsigned short* xp =
          (const unsigned short*)x + ((size_t)(b * NC + c0)) * NN + n0 + pq;
#pragma unroll
      for (int i = 0; i < 8; i++) {
        ushort4 r = *(const ushort4*)(xp + (size_t)i * NN);
        hi[i][0] = r.x; hi[i][1] = r.y; hi[i][2] = r.z; hi[i][3] = r.w;
      }
    } else {
      const float* xp = (const float*)x + ((size_t)(b * NC + c0)) * NN + n0 + pq;
#pragma unroll
      for (int i = 0; i < 8; i++) {
        float4 v = *(const float4*)(xp + (size_t)i * NN);
        float vv[4] = {v.x, v.y, v.z, v.w};
#pragma unroll
        for (int j = 0; j < 4; j++) {
          unsigned short hh = f2u(vv[j]);
          hi[i][j] = hh;
          lo[i][j] = f2u(vv[j] - u2f(hh));
        }
      }
    }
#pragma unroll
    for (int j = 0; j < 4; j++) {
      int p = pq + j;
      uint4 wv;
      wv.x = hi[0][j] | ((unsigned)hi[1][j] << 16);
      wv.y = hi[2][j] | ((unsigned)hi[3][j] << 16);
      wv.z = hi[4][j] | ((unsigned)hi[5][j] << 16);
      wv.w = hi[6][j] | ((unsigned)hi[7][j] << 16);
      *(uint4*)lds_at(pool + XT_O, p, c0 * 2) = wv;
      if (!ISBF) {
        uint4 wl2;
        wl2.x = lo[0][j] | ((unsigned)lo[1][j] << 16);
        wl2.y = lo[2][j] | ((unsigned)lo[3][j] << 16);
        wl2.z = lo[4][j] | ((unsigned)lo[5][j] << 16);
        wl2.w = lo[6][j] | ((unsigned)lo[7][j] << 16);
        *(uint4*)lds_at(pool + XTL_O, p, c0 * 2) = wl2;
      }
    }
  }
  __syncthreads();

  // ---- GEMM1: q = Wq @ x (fp32: 6-term) ----
  f32x4 acc[4][2];
#pragma unroll
  for (int mi = 0; mi < 4; mi++) { acc[mi][0] = zero4; acc[mi][1] = zero4; }
  {
    const bf16x8* Aq = (const bf16x8*)WqPh;
    const bf16x8* Aql = (const bf16x8*)WqPl;
#pragma unroll
    for (int kt = 0; kt < 8; kt++) {
      bf16x8 xb0 = *(const bf16x8*)lds_at(pool + XT_O, cc, kt * 64 + 16 * g);
      bf16x8 xb1 = *(const bf16x8*)lds_at(pool + XT_O, 16 + cc, kt * 64 + 16 * g);
      bf16x8 av[4];
#pragma unroll
      for (int mi = 0; mi < 4; mi++) av[mi] = Aq[(kt * 16 + w * 4 + mi) * 64 + l];
#pragma unroll
      for (int mi = 0; mi < 4; mi++) {
        acc[mi][0] = MFMA16(av[mi], xb0, acc[mi][0]);
        acc[mi][1] = MFMA16(av[mi], xb1, acc[mi][1]);
      }
      if (!ISBF) {
        bf16x8 xl0 = *(const bf16x8*)lds_at(pool + XTL_O, cc, kt * 64 + 16 * g);
        bf16x8 xl1 = *(const bf16x8*)lds_at(pool + XTL_O, 16 + cc, kt * 64 + 16 * g);
#pragma unroll
        for (int mi = 0; mi < 4; mi++) {
          bf16x8 al2 = Aql[(kt * 16 + w * 4 + mi) * 64 + l];
          acc[mi][0] = MFMA16(av[mi], xl0, acc[mi][0]);
          acc[mi][1] = MFMA16(av[mi], xl1, acc[mi][1]);
          acc[mi][0] = MFMA16(al2, xb0, acc[mi][0]);
          acc[mi][1] = MFMA16(al2, xb1, acc[mi][1]);
        }
      }
    }
  }

  // ---- softmax over D per (head,pixel); E hi/lo -> SM tiles ----
  float inv_s[2][2];
#pragma unroll
  for (int hp = 0; hp < 2; hp++) {
#pragma unroll
    for (int ni = 0; ni < 2; ni++) {
      float e8[8];
      float mx = -3.0e38f;
#pragma unroll
      for (int mi2 = 0; mi2 < 2; mi2++) {
#pragma unroll
        for (int r = 0; r < 4; r++) {
          int o = w * 64 + (2 * hp + mi2) * 16 + 4 * g + r;
          float v = acc[2 * hp + mi2][ni][r] * qs_l[o] + qb_l[o];
          e8[mi2 * 4 + r] = v;
          mx = fmaxf(mx, v);
        }
      }
      mx = fmaxf(mx, __shfl_xor(mx, 16, 64));
      mx = fmaxf(mx, __shfl_xor(mx, 32, 64));
      float s = 0.f;
#pragma unroll
      for (int i2 = 0; i2 < 8; i2++) { e8[i2] = __expf(e8[i2] - mx); s += e8[i2]; }
      s += __shfl_xor(s, 16, 64);
      s += __shfl_xor(s, 32, 64);
      inv_s[hp][ni] = 1.f / s;
      int p = ni * 16 + cc;
#pragma unroll
      for (int mi2 = 0; mi2 < 2; mi2++) {
        int colb = (w * 64 + (2 * hp + mi2) * 16 + 4 * g) * 2;
        unsigned short h[4], lo2[4];
#pragma unroll
        for (int r = 0; r < 4; r++) {
          float ev = e8[mi2 * 4 + r];
          unsigned short hh = f2u(ev);
          h[r] = hh;
          lo2[r] = f2u(ev - u2f(hh));
        }
        uint2 wh, wl2;
        wh.x = h[0] | ((unsigned)h[1] << 16);
        wh.y = h[2] | ((unsigned)h[3] << 16);
        wl2.x = lo2[0] | ((unsigned)lo2[1] << 16);
        wl2.y = lo2[2] | ((unsigned)lo2[3] << 16);
        *(uint2*)lds_at(pool + SMH_O, p, colb) = wh;
        *(uint2*)lds_at(pool + SML_O, p, colb) = wl2;
      }
    }
  }
  __syncthreads();  // (1) all XT reads done; SM tiles complete

  // ---- ctx GEMM: att = ctx^T @ E (fp32 4-term), /s, relu, hi/lo -> YT tiles ----
#pragma unroll
  for (int hp = 0; hp < 2; hp++) {
    f32x4 cacc[2][2];
#pragma unroll
    for (int mp = 0; mp < 2; mp++) { cacc[mp][0] = zero4; cacc[mp][1] = zero4; }
#pragma unroll
    for (int ni = 0; ni < 2; ni++) {
      int p = ni * 16 + cc;
      int colb = ((2 * w + hp) * 32 + 8 * g) * 2;
      bf16x8 bh = *(const bf16x8*)lds_at(pool + SMH_O, p, colb);
      bf16x8 bl = *(const bf16x8*)lds_at(pool + SML_O, p, colb);
#pragma unroll
      for (int mp = 0; mp < 2; mp++) {
        cacc[mp][ni] = MFMA16(cAh[mp], bh, cacc[mp][ni]);
        cacc[mp][ni] = MFMA16(cAh[mp], bl, cacc[mp][ni]);
        cacc[mp][ni] = MFMA16(cAl[mp], bh, cacc[mp][ni]);
        if (!ISBF) cacc[mp][ni] = MFMA16(cAl[mp], bl, cacc[mp][ni]);
      }
    }
#pragma unroll
    for (int mp = 0; mp < 2; mp++) {
#pragma unroll
      for (int ni = 0; ni < 2; ni++) {
        int p = ni * 16 + cc;
        float iv = inv_s[hp][ni];
        unsigned short h[4], lo2[4];
#pragma unroll
        for (int r = 0; r < 4; r++) {
          float y = fmaxf(cacc[mp][ni][r] * iv, 0.f);
          unsigned short hh = f2u(y);
          h[r] = hh;
          lo2[r] = f2u(y - u2f(hh));
        }
        int colb = ((2 * w + hp) * 32 + mp * 16 + 4 * g) * 2;
        uint2 wh;
        wh.x = h[0] | ((unsigned)h[1] << 16);
        wh.y = h[2] | ((unsigned)h[3] << 16);
        *(uint2*)lds_at(pool + YTH_O, p, colb) = wh;
        if (!ISBF) {
          uint2 wl2;
          wl2.x = lo2[0] | ((unsigned)lo2[1] << 16);
          wl2.y = lo2[2] | ((unsigned)lo2[3] << 16);
          *(uint2*)lds_at(pool + YTL_O, p, colb) = wl2;
        }
      }
    }
  }
  __syncthreads();  // (2) YT tiles complete

  // ---- GEMM2: out = Wp @ relu(att) (bf16: 2-term, fp32: 6-term) ----
  f32x4 oacc[4][2];
#pragma unroll
  for (int mi = 0; mi < 4; mi++) { oacc[mi][0] = zero4; oacc[mi][1] = zero4; }
  {
    const bf16x8* Ap = (const bf16x8*)WpPh;
    const bf16x8* Apl = (const bf16x8*)WpPl;
#pragma unroll
    for (int kt = 0; kt < 8; kt++) {
      bf16x8 yh0 = *(const bf16x8*)lds_at(pool + YTH_O, cc, kt * 64 + 16 * g);
      bf16x8 yh1 = *(const bf16x8*)lds_at(pool + YTH_O, 16 + cc, kt * 64 + 16 * g);
      bf16x8 av[4];
#pragma unroll
      for (int mi = 0; mi < 4; mi++) av[mi] = Ap[(kt * 16 + w * 4 + mi) * 64 + l];
#pragma unroll
      for (int mi = 0; mi < 4; mi++) {
        oacc[mi][0] = MFMA16(av[mi], yh0, oacc[mi][0]);
        oacc[mi][1] = MFMA16(av[mi], yh1, oacc[mi][1]);
      }
      if (!ISBF) {
        bf16x8 yl0 = *(const bf16x8*)lds_at(pool + YTL_O, cc, kt * 64 + 16 * g);
        bf16x8 yl1 = *(const bf16x8*)lds_at(pool + YTL_O, 16 + cc, kt * 64 + 16 * g);
#pragma unroll
        for (int mi = 0; mi < 4; mi++) {
          bf16x8 al2 = Apl[(kt * 16 + w * 4 + mi) * 64 + l];
          oacc[mi][0] = MFMA16(av[mi], yl0, oacc[mi][0]);
          oacc[mi][1] = MFMA16(av[mi], yl1, oacc[mi][1]);
          oacc[mi][0] = MFMA16(al2, yh0, oacc[mi][0]);
          oacc[mi][1] = MFMA16(al2, yh1, oacc[mi][1]);
        }
      }
    }
  }

  // ---- epilogue: affine -> OT (channel-major) -> coalesced global store ----
  {
    char* OT = pool + OT_O;
#pragma unroll
    for (int mi = 0; mi < 4; mi++) {
#pragma unroll
      for (int ni = 0; ni < 2; ni++) {
#pragma unroll
        for (int r = 0; r < 4; r++) {
          int o = w * 64 + mi * 16 + 4 * g + r;
          float v = oacc[mi][ni][r] * ps_l[o] + pb_l[o];
          int p = ni * 16 + cc;
          if (ISBF)
            *(unsigned short*)(OT + o * OT_STR + p * 2) = f2u(v);
          else
            *(float*)(OT + o * OT_STR + p * 4) = v;
        }
      }
    }
  }
  __syncthreads();  // (3) OT complete
  {
    char* OT = pool + OT_O;
    int o = tid;
    size_t gbase = ((size_t)(b * NC + o)) * NN + n0;
    if (ISBF) {
      unsigned short* po = (unsigned short*)out + gbase;
#pragma unroll
      for (int k = 0; k < 4; k++) {
        uint2 a = *(const uint2*)(OT + o * OT_STR + k * 16);
        uint2 b2 = *(const uint2*)(OT + o * OT_STR + k * 16 + 8);
        *(uint4*)(po + k * 8) = make_uint4(a.x, a.y, b2.x, b2.y);
      }
    } else {
      float* po = (float*)out + gbase;
#pragma unroll
      for (int k = 0; k < 8; k++)
        *(float4*)(po + k * 4) = *(const float4*)(OT + o * OT_STR + k * 16);
    }
  }
}

extern "C" void kernel_launch(void* const* d_in, const int* in_sizes, int n_in,
                              void* d_out, int out_size, void* d_ws, size_t ws_size,
                              hipStream_t stream) {
  const void* input   = d_in[0];
  const void* wq      = d_in[1];
  const void* q_scale = d_in[2];
  const void* q_bias  = d_in[3];
  const void* wkv     = d_in[4];
  const void* kv_scale= d_in[5];
  const void* kv_bias = d_in[6];
  const void* wp      = d_in[7];
  const void* p_scale = d_in[8];
  const void* p_bias  = d_in[9];

  char* w = (char*)d_ws;
  int*  flag = (int*)w;      w += 256;
  float* Spart = (float*)w;  w += (size_t)1024 * 1024 * 4;   // 4 MiB
  float* Zpart = (float*)w;  w += (size_t)2048 * ND * 4;     // 256 KiB
  float* ctx  = (float*)w;   w += (size_t)NB * ND * ND * 4;  // 32 KiB
  unsigned short* WqPh = (unsigned short*)w; w += (size_t)NC * NC * 2;
  unsigned short* WqPl = (unsigned short*)w; w += (size_t)NC * NC * 2;
  unsigned short* WpPh = (unsigned short*)w; w += (size_t)NC * NC * 2;
  unsigned short* WpPl = (unsigned short*)w; w += (size_t)NC * NC * 2;
  unsigned short* WkPh = (unsigned short*)w; w += (size_t)ND * NC * 2;
  unsigned short* WkPl = (unsigned short*)w; w += (size_t)ND * NC * 2;

  detect_kernel<<<1, 256, 0, stream>>>(input, flag);
  prep_weights<<<68, 256, 0, stream>>>(wq, wp, wkv, flag, WqPh, WqPl, WpPh, WpPl,
                                       WkPh, WkPl);
  kv_ctx<1><<<1024, 256, 0, stream>>>(input, WkPh, WkPl, kv_scale, kv_bias, flag,
                                      Spart, Zpart);
  kv_ctx<0><<<1024, 256, 0, stream>>>(input, WkPh, WkPl, kv_scale, kv_bias, flag,
                                      Spart, Zpart);
  ctx_redfin<<<256, 256, 0, stream>>>(Spart, Zpart, ctx);
  fused_main<1><<<4096, 256, 0, stream>>>(input, WqPh, WqPl, WpPh, WpPl,
                                          q_scale, q_bias, p_scale, p_bias,
                                          ctx, flag, (void*)d_out);
  fused_main<0><<<4096, 256, 0, stream>>>(input, WqPh, WqPl, WpPh, WpPl,
                                          q_scale, q_bias, p_scale, p_bias,
                                          ctx, flag, (void*)d_out);
}